// Round 9
// baseline (180.527 us; speedup 1.0000x reference)
//
#include <hip/hip_runtime.h>

// ---------------------------------------------------------------------------
// ConvFeatureExtractor: profile = rownorm( freq @ softmax(matches/T, axis=1)^T )
//   matches[f,i] = Thi[f, i>>6] + Tlo[f, i&63]  (separable!), F=8192, M=4096,
//   B=1024, K=6.  =>  probs[f,i] = e1[f,i>>6] * e2[f,i&63],  Z = (sum e1)(sum e2).
// R15: BARRIER-FREE gemm. All barrier-synced variants pin at 35-39% MfmaUtil
//   (R6/R9/R10/R14): per block, all 4 waves share the {vmcnt,barrier,ds-lat}
//   window so the MFMA pipe idles ~50%/kt; R14's k-rotation proved index
//   shifts don't move time-phase. New structure: 1 wave per block (64 thr),
//   wave owns a 64x64 output tile + PRIVATE 2x8KB LDS A double-buffer ->
//   zero __syncthreads. Per kt: vmcnt(0) [own stage, issued a full compute
//   phase ago] -> ds_read (R10's proven XOR swizzle) -> stage(kt+1) ->
//   32 MFMA + e1 fold. Waves self-pace and drift; one wave's MFMA burst
//   covers the other's latency window. 8 blocks/CU (LDS 16KB, VGPR~190,
//   launch_bounds(64,2)); grid 2048 all-resident; XCD remap keeps each
//   XCD's 1MB A-slice L2-pinned (traffic ~3.2 TB/s/XCD < 4.3 ceiling).
//   Dataflow unchanged (R9): pooled = sum_kt e1'[f,kt]*(A_kt x e2), MFMA on
//   constant e2 frags, e1 folded as f32 per-lane scalar.
// ---------------------------------------------------------------------------

typedef __bf16  bf16x8 __attribute__((ext_vector_type(8)));
typedef float   f32x4  __attribute__((ext_vector_type(4)));

#define GLD16(gp, lp)                                                          \
  __builtin_amdgcn_global_load_lds(                                            \
      (const __attribute__((address_space(1))) void*)(gp),                     \
      (__attribute__((address_space(3))) void*)(lp), 16, 0, 0)

__device__ __forceinline__ short f2bf(float x) {
  unsigned u = __float_as_uint(x);
  unsigned r = (u + 0x7fffu + ((u >> 16) & 1u)) >> 16;   // RNE
  return (short)r;
}

__device__ __forceinline__ float wave_max(float v) {
  #pragma unroll
  for (int off = 32; off; off >>= 1) v = fmaxf(v, __shfl_xor(v, off, 64));
  return v;
}
__device__ __forceinline__ float wave_sum(float v) {
  #pragma unroll
  for (int off = 32; off; off >>= 1) v += __shfl_xor(v, off, 64);
  return v;
}

// ---------------- k1: prep = cast (blocks 0..4095) + tables (4096..6143) ----
__global__ __launch_bounds__(256) void prep_kernel(const float* __restrict__ freq,
                                                   short* __restrict__ freqb,
                                                   const float* __restrict__ kp,
                                                   const float* __restrict__ temp,
                                                   float* __restrict__ E1t,
                                                   float* __restrict__ E2) {
  if (blockIdx.x < 4096) {
    int idx = blockIdx.x * 256 + threadIdx.x;
    float4 v = ((const float4*)freq)[idx];
    short4 o;
    o.x = f2bf(v.x); o.y = f2bf(v.y); o.z = f2bf(v.z); o.w = f2bf(v.w);
    ((short4*)freqb)[idx] = o;
  } else {
    const int t = threadIdx.x;
    const int lane = t & 63, wave = t >> 6;
    const int f = (blockIdx.x - 4096) * 4 + wave;
    const float* P = kp + f * 24;
    const int d0 = (lane >> 4) & 3, d1 = (lane >> 2) & 3, d2 = lane & 3;
    const float thi = P[d0 * 6 + 0] + P[d1 * 6 + 1] + P[d2 * 6 + 2];
    const float tlo = P[d0 * 6 + 3] + P[d1 * 6 + 4] + P[d2 * 6 + 5];
    const float mxhi = wave_max(thi), mxlo = wave_max(tlo);
    const float invT = 1.0f / temp[0];
    const float e1 = __expf((thi - mxhi) * invT);
    const float e2 = __expf((tlo - mxlo) * invT);
    const float s1 = wave_sum(e1), s2 = wave_sum(e2);
    const float invZ = 1.0f / (s1 * s2);
    E1t[lane * 8192 + f] = e1 * invZ;
    E2[(size_t)f * 64 + lane] = e2;
  }
}

// ---------------- k2: GEMM pooled = A(1024x4096) * B^T, B[f,i]=e1[f,i>>6]e2[f,i&63]
// One wave per block; wave tile 64m x 64n = 4x4 frags of 16x16x32; BK=64.
// Private 2x8KB LDS double buffer; no barriers. Grid 2048 (8/CU resident).
__global__ __launch_bounds__(64, 2) void gemm_kernel(const short* __restrict__ A,
                                                     const float* __restrict__ E1t,
                                                     const float* __restrict__ E2,
                                                     float* __restrict__ C) {
  __shared__ short As[2][64 * 64];               // 2 x 8 KiB, wave-private

  const int lane = threadIdx.x;                  // 64-thread block = 1 wave
  const int quad = lane >> 4, l16 = lane & 15;

  // XCD-aware remap: XCD k = d%8 owns L in [256k,256k+256) = m-strips
  // {2k,2k+1} -> 1MB A slice per XCD, L2-pinned. n varies fastest.
  const int d  = blockIdx.x;
  const int L  = (d & 7) * 256 + (d >> 3);
  const int m0 = (L >> 7) * 64;                  // batch tile (16 strips)
  const int n0 = (L & 127) * 64;                 // filter tile (128 strips)

  f32x4 acc[4][4];
  #pragma unroll
  for (int i = 0; i < 4; i++)
    #pragma unroll
    for (int j = 0; j < 4; j++) acc[i][j] = (f32x4){0.f, 0.f, 0.f, 0.f};

  // constant bf16 e2 fragments: lane (l16,quad) of frag (ks,j) covers
  // k = (ks*4+quad)*8 + 0..7 for filter row nrow[j]
  int nrow[4];
  #pragma unroll
  for (int j = 0; j < 4; j++) nrow[j] = n0 + j * 16 + l16;
  bf16x8 e2f[2][4];
  #pragma unroll
  for (int j = 0; j < 4; j++)
    #pragma unroll
    for (int ks = 0; ks < 2; ks++) {
      const float* p = E2 + (size_t)nrow[j] * 64 + (ks * 4 + quad) * 8;
      float4 lo = *(const float4*)p, hi = *(const float4*)(p + 4);
      bf16x8 bb;
      bb[0] = (__bf16)lo.x; bb[1] = (__bf16)lo.y;
      bb[2] = (__bf16)lo.z; bb[3] = (__bf16)lo.w;
      bb[4] = (__bf16)hi.x; bb[5] = (__bf16)hi.y;
      bb[6] = (__bf16)hi.z; bb[7] = (__bf16)hi.w;
      e2f[ks][j] = bb;
    }

  // staging (R10's proven pattern, 8 chunks now all by this wave):
  // chunk c covers rows 8c..8c+7; lane -> (row=8c+(lane>>3), col=((lane&7)^
  // (lane>>3))*8 shorts); LDS dest linear = chunk*512 + lane*8.
  const int lane_row = lane >> 3;                      // 0..7 within 8-row chunk
  const int src_col = ((lane & 7) ^ lane_row) * 8;     // swizzled global col (shorts)
  const int sw = l16 & 7;                              // reader swizzle key (= row&7)
  const short* Abase = A + (size_t)(m0 + lane_row) * 4096 + src_col;

  #define STG(kt, buf) do {                                                    \
    _Pragma("unroll")                                                          \
    for (int c = 0; c < 8; c++)                                                \
      GLD16(Abase + (size_t)(c * 8) * 4096 + (kt) * 64,                        \
            &As[buf][c * 512 + lane * 8]);                                     \
  } while (0)

  // prologue: stage tile 0, load e1(0)
  STG(0, 0);
  float e1n[4], e1c[4];
  #pragma unroll
  for (int j = 0; j < 4; j++) e1n[j] = E1t[nrow[j]];

  const f32x4 Z4 = (f32x4){0.f, 0.f, 0.f, 0.f};

  #pragma unroll 1
  for (int kt = 0; kt < 64; ++kt) {
    const int cb = kt & 1;
    const int tn = (kt + 1 > 63) ? 63 : kt + 1;        // tail: dummy restage

    // own stage(kt) + e1(kt) landed (issued a full compute phase ago).
    // No barrier: buffer is wave-private.
    asm volatile("s_waitcnt vmcnt(0)" ::: "memory");
    __builtin_amdgcn_sched_barrier(0);

    bf16x8 a[4][2];
    #pragma unroll
    for (int i = 0; i < 4; i++)
      #pragma unroll
      for (int ks = 0; ks < 2; ks++)
        a[i][ks] = *(const bf16x8*)&As[cb][(i * 16 + l16) * 64 +
                                          (((ks * 4 + quad) ^ sw) * 8)];

    #pragma unroll
    for (int j = 0; j < 4; j++) e1c[j] = e1n[j];

    STG(tn, cb ^ 1);                                   // prefetch next tile
    #pragma unroll
    for (int j = 0; j < 4; j++) e1n[j] = E1t[tn * 8192 + nrow[j]];

    __builtin_amdgcn_s_setprio(1);
    #pragma unroll
    for (int j = 0; j < 4; j++) {
      const f32x4 s4 = (f32x4){e1c[j], e1c[j], e1c[j], e1c[j]};
      #pragma unroll
      for (int i = 0; i < 4; i++) {
        f32x4 P = __builtin_amdgcn_mfma_f32_16x16x32_bf16(a[i][0], e2f[0][j], Z4, 0, 0, 0);
        P = __builtin_amdgcn_mfma_f32_16x16x32_bf16(a[i][1], e2f[1][j], P, 0, 0, 0);
        acc[i][j] += s4 * P;                           // f32 fold of e1
      }
    }
    __builtin_amdgcn_s_setprio(0);
  }

  asm volatile("s_waitcnt vmcnt(0)" ::: "memory");     // drain tail dummy stage

  // epilogue: C/D layout col=lane&15, row=quad*4+reg
  #pragma unroll
  for (int i = 0; i < 4; i++) {
    #pragma unroll
    for (int r = 0; r < 4; r++) {
      const int brow = m0 + i * 16 + quad * 4 + r;
      float* crow = C + (size_t)brow * 8192 + n0 + l16;
      #pragma unroll
      for (int j = 0; j < 4; j++) crow[j * 16] = acc[i][j][r];
    }
  }
  #undef STG
}

// ---------------- k3: row-normalize d_out (1024 rows of 8192) ----------------
__global__ __launch_bounds__(256) void norm_kernel(float* __restrict__ out) {
  const int b = blockIdx.x;
  const int t = threadIdx.x;
  const int lane = t & 63, wave = t >> 6;
  __shared__ float red[4];

  float4* row = (float4*)(out + (size_t)b * 8192);   // 2048 float4
  float4 v[8];
  float s = 0.0f;
  #pragma unroll
  for (int q = 0; q < 8; q++) {
    v[q] = row[q * 256 + t];
    s += (v[q].x + v[q].y) + (v[q].z + v[q].w);
  }
  float ws = wave_sum(s);
  if (lane == 0) red[wave] = ws;
  __syncthreads();
  float tot = (red[0] + red[1]) + (red[2] + red[3]);
  float inv = 1.0f / tot;
  #pragma unroll
  for (int q = 0; q < 8; q++) {
    v[q].x *= inv; v[q].y *= inv; v[q].z *= inv; v[q].w *= inv;
    row[q * 256 + t] = v[q];
  }
}

// ---------------------------------------------------------------------------
extern "C" void kernel_launch(void* const* d_in, const int* in_sizes, int n_in,
                              void* d_out, int out_size, void* d_ws, size_t ws_size,
                              hipStream_t stream) {
  const float* freq    = (const float*)d_in[0];   // 1024*4096
  const float* kparams = (const float*)d_in[1];   // 8192*4*6
  const float* temp    = (const float*)d_in[2];   // 1
  // d_in[3] = kmer_idcs (recomputed analytically in-kernel)

  float* out = (float*)d_out;                     // 1024*8192 f32

  short* freqb = (short*)d_ws;                    // 1024*4096 bf16 = 8 MiB
  float* E1t   = (float*)(freqb + (size_t)1024 * 4096);  // 64*8192 f32 = 2 MiB
  float* E2    = E1t + (size_t)64 * 8192;                // 8192*64 f32 = 2 MiB

  prep_kernel<<<6144, 256, 0, stream>>>(freq, freqb, kparams, temp, E1t, E2);
  gemm_kernel<<<2048, 64, 0, stream>>>(freqb, E1t, E2, out);
  norm_kernel<<<1024, 256, 0, stream>>>(out);
}

// Round 10
// 160.387 us; speedup vs baseline: 1.1256x; 1.1256x over previous
//
#include <hip/hip_runtime.h>

// ---------------------------------------------------------------------------
// ConvFeatureExtractor: profile = rownorm( freq @ softmax(matches/T, axis=1)^T )
//   matches[f,i] = Thi[f, i>>6] + Tlo[f, i&63]  (separable!), F=8192, M=4096,
//   B=1024, K=6.  =>  probs[f,i] = e1[f,i>>6] * e2[f,i&63],  Z = (sum e1)(sum e2).
// R16: producer->consumer L2 locality. R15 proved the gemm stall is load-
//   return latency (barrier-free variant: 100us); R10's structure stays.
//   New: (1) cast blocks XCD-remapped (g=(d%8)*512+d/8) so XCD k writes
//   freqb rows [128k,128k+128) -- the exact 1MB slice gemm's XCD k re-reads
//   64x. Staged A-loads then hit local L2 (~200cyc) instead of HBM (~900),
//   shrinking the per-kt naked window. (2) norm blocks XCD-remapped
//   (b=(d%8)*128+d/8) so each row is normalized on the XCD holding it dirty
//   in L2. Pure bijective permutations; kernels otherwise = R10/R11.
//   Ledger: R7/R8 template ports regress; R11 no-LDS 17% Mfma; R12 grid
//   barrier 212us; R13 analytic norm net-negative; R14 k-rotation null.
// ---------------------------------------------------------------------------

typedef __bf16  bf16x8 __attribute__((ext_vector_type(8)));
typedef float   f32x4  __attribute__((ext_vector_type(4)));

#define GLD16(gp, lp)                                                          \
  __builtin_amdgcn_global_load_lds(                                            \
      (const __attribute__((address_space(1))) void*)(gp),                     \
      (__attribute__((address_space(3))) void*)(lp), 16, 0, 0)

__device__ __forceinline__ short f2bf(float x) {
  unsigned u = __float_as_uint(x);
  unsigned r = (u + 0x7fffu + ((u >> 16) & 1u)) >> 16;   // RNE
  return (short)r;
}

__device__ __forceinline__ float wave_max(float v) {
  #pragma unroll
  for (int off = 32; off; off >>= 1) v = fmaxf(v, __shfl_xor(v, off, 64));
  return v;
}
__device__ __forceinline__ float wave_sum(float v) {
  #pragma unroll
  for (int off = 32; off; off >>= 1) v += __shfl_xor(v, off, 64);
  return v;
}

// ---------------- k1: prep = cast (blocks 0..4095) + tables (4096..6143) ----
// cast blocks XCD-remapped: dispatch d -> g=(d%8)*512+d/8, so XCD k (=d%8)
// writes freqb rows [128k,128k+128) = the slice gemm's XCD k consumes.
__global__ __launch_bounds__(256) void prep_kernel(const float* __restrict__ freq,
                                                   short* __restrict__ freqb,
                                                   const float* __restrict__ kp,
                                                   const float* __restrict__ temp,
                                                   float* __restrict__ E1t,
                                                   float* __restrict__ E2) {
  if (blockIdx.x < 4096) {
    const int d = blockIdx.x;
    const int g = (d & 7) * 512 + (d >> 3);      // bijective XCD remap
    int idx = g * 256 + threadIdx.x;
    float4 v = ((const float4*)freq)[idx];
    short4 o;
    o.x = f2bf(v.x); o.y = f2bf(v.y); o.z = f2bf(v.z); o.w = f2bf(v.w);
    ((short4*)freqb)[idx] = o;
  } else {
    const int t = threadIdx.x;
    const int lane = t & 63, wave = t >> 6;
    const int f = (blockIdx.x - 4096) * 4 + wave;
    const float* P = kp + f * 24;
    const int d0 = (lane >> 4) & 3, d1 = (lane >> 2) & 3, d2 = lane & 3;
    const float thi = P[d0 * 6 + 0] + P[d1 * 6 + 1] + P[d2 * 6 + 2];
    const float tlo = P[d0 * 6 + 3] + P[d1 * 6 + 4] + P[d2 * 6 + 5];
    const float mxhi = wave_max(thi), mxlo = wave_max(tlo);
    const float invT = 1.0f / temp[0];
    const float e1 = __expf((thi - mxhi) * invT);
    const float e2 = __expf((tlo - mxlo) * invT);
    const float s1 = wave_sum(e1), s2 = wave_sum(e2);
    const float invZ = 1.0f / (s1 * s2);
    E1t[lane * 8192 + f] = e1 * invZ;
    E2[(size_t)f * 64 + lane] = e2;
  }
}

// ---------------- k2: GEMM pooled = A(1024x4096) * B^T, B[f,i]=e1[f,i>>6]e2[f,i&63]
// TM=64, TN=128, BK=64; grid 1024 blocks (4/CU), 4 waves 1Mx4N (wave 64x32).
// R10 loop: XCD remap (XCD k owns m-strips {2k,2k+1}), 3-deep 8KB A buffers,
// 1 barrier/kt, counted vmcnt(4), re-associated e1 fold (MFMA on const e2).
__global__ __launch_bounds__(256, 4) void gemm_kernel(const short* __restrict__ A,
                                                      const float* __restrict__ E1t,
                                                      const float* __restrict__ E2,
                                                      float* __restrict__ C) {
  __shared__ short As[3][64 * 64];               // 3 x 8 KiB rotating buffers

  const int t = threadIdx.x;
  const int lane = t & 63, wave = t >> 6;
  const int quad = lane >> 4, l16 = lane & 15;

  const int d  = blockIdx.y * 64 + blockIdx.x;
  const int L  = (d & 7) * 128 + (d >> 3);
  const int m0 = (L >> 6) * 64;                  // batch tile (16 strips)
  const int n0 = (L & 63) * 128;                 // filter tile (64 strips)
  const int wn = wave * 32;                      // wave's n-offset

  f32x4 acc[4][2];
  #pragma unroll
  for (int i = 0; i < 4; i++)
    #pragma unroll
    for (int j = 0; j < 2; j++) acc[i][j] = (f32x4){0.f, 0.f, 0.f, 0.f};

  // constant bf16 e2 fragments: lane (l16,quad) of frag (ks,j) covers
  // k = (ks*4+quad)*8 + 0..7 for filter row nrow[j]
  int nrow[2];
  #pragma unroll
  for (int j = 0; j < 2; j++) nrow[j] = n0 + wn + j * 16 + l16;
  bf16x8 e2f[2][2];
  #pragma unroll
  for (int j = 0; j < 2; j++)
    #pragma unroll
    for (int ks = 0; ks < 2; ks++) {
      const float* p = E2 + (size_t)nrow[j] * 64 + (ks * 4 + quad) * 8;
      float4 lo = *(const float4*)p, hi = *(const float4*)(p + 4);
      bf16x8 bb;
      bb[0] = (__bf16)lo.x; bb[1] = (__bf16)lo.y;
      bb[2] = (__bf16)lo.z; bb[3] = (__bf16)lo.w;
      bb[4] = (__bf16)hi.x; bb[5] = (__bf16)hi.y;
      bb[6] = (__bf16)hi.z; bb[7] = (__bf16)hi.w;
      e2f[ks][j] = bb;
    }

  const int lane_row = lane >> 3;                      // 0..7 within 8-row chunk
  const int src_col = ((lane & 7) ^ lane_row) * 8;     // swizzled global col (shorts)
  const int sw = l16 & 7;                              // reader swizzle key (= row&7)
  const int chunk = wave * 2;                          // wave stages chunks 2w, 2w+1
  const short* Abase = A + (size_t)(m0 + lane_row) * 4096 + src_col;

  #define STG(kt, buf) do {                                                    \
    GLD16(Abase + (size_t)((chunk + 0) * 8) * 4096 + (kt) * 64,                \
          &As[buf][(chunk + 0) * 512 + lane * 8]);                             \
    GLD16(Abase + (size_t)((chunk + 1) * 8) * 4096 + (kt) * 64,                \
          &As[buf][(chunk + 1) * 512 + lane * 8]);                             \
  } while (0)

  // prologue: S(0), e1(0), S(1)  -> 6 VMEM outstanding
  STG(0, 0);
  float e1n[2], e1c[2];
  #pragma unroll
  for (int j = 0; j < 2; j++) e1n[j] = E1t[nrow[j]];
  STG(1, 1);

  const f32x4 Z4 = (f32x4){0.f, 0.f, 0.f, 0.f};

  #pragma unroll 1
  for (int kt = 0; kt < 64; ++kt) {
    const int cb = kt % 3;
    const int sb = (kt + 2) % 3;
    const int tn = (kt + 1 > 63) ? 63 : kt + 1;        // tail: dummy reload
    const int ts = (kt + 2 > 63) ? 63 : kt + 2;        // tail: dummy restage

    asm volatile("s_waitcnt vmcnt(4)" ::: "memory");   // S(kt) landed
    __builtin_amdgcn_s_barrier();                      // publish tile kt

    bf16x8 a[4][2];
    #pragma unroll
    for (int i = 0; i < 4; i++)
      #pragma unroll
      for (int ks = 0; ks < 2; ks++)
        a[i][ks] = *(const bf16x8*)&As[cb][(i * 16 + l16) * 64 +
                                          (((ks * 4 + quad) ^ sw) * 8)];

    #pragma unroll
    for (int j = 0; j < 2; j++) e1c[j] = e1n[j];
    #pragma unroll
    for (int j = 0; j < 2; j++) e1n[j] = E1t[tn * 8192 + nrow[j]];  // +2 VMEM
    STG(ts, sb);                                                    // +2 VMEM

    __builtin_amdgcn_s_setprio(1);
    #pragma unroll
    for (int j = 0; j < 2; j++) {
      const f32x4 s4 = (f32x4){e1c[j], e1c[j], e1c[j], e1c[j]};
      #pragma unroll
      for (int i = 0; i < 4; i++) {
        f32x4 P = __builtin_amdgcn_mfma_f32_16x16x32_bf16(a[i][0], e2f[0][j], Z4, 0, 0, 0);
        P = __builtin_amdgcn_mfma_f32_16x16x32_bf16(a[i][1], e2f[1][j], P, 0, 0, 0);
        acc[i][j] += s4 * P;                           // f32 fold of e1
      }
    }
    __builtin_amdgcn_s_setprio(0);
    // no bottom barrier: restage target (kt+2)%3 last read at kt-1, ordered
    // by this kt's top barrier.
  }

  asm volatile("s_waitcnt vmcnt(0)" ::: "memory");     // drain tail dummies

  // epilogue: C/D layout col=lane&15, row=quad*4+reg
  #pragma unroll
  for (int i = 0; i < 4; i++) {
    #pragma unroll
    for (int r = 0; r < 4; r++) {
      const int brow = m0 + i * 16 + quad * 4 + r;
      float* crow = C + (size_t)brow * 8192 + n0 + wn + l16;
      #pragma unroll
      for (int j = 0; j < 2; j++) crow[j * 16] = acc[i][j][r];
    }
  }
  #undef STG
}

// ---------------- k3: row-normalize d_out (1024 rows of 8192) ----------------
// XCD-remapped: dispatch d -> row b=(d%8)*128+d/8, so row b is normalized on
// XCD b>>7 -- the XCD that just wrote it (dirty in its L2).
__global__ __launch_bounds__(256) void norm_kernel(float* __restrict__ out) {
  const int b = (blockIdx.x & 7) * 128 + (blockIdx.x >> 3);   // bijective remap
  const int t = threadIdx.x;
  const int lane = t & 63, wave = t >> 6;
  __shared__ float red[4];

  float4* row = (float4*)(out + (size_t)b * 8192);   // 2048 float4
  float4 v[8];
  float s = 0.0f;
  #pragma unroll
  for (int q = 0; q < 8; q++) {
    v[q] = row[q * 256 + t];
    s += (v[q].x + v[q].y) + (v[q].z + v[q].w);
  }
  float ws = wave_sum(s);
  if (lane == 0) red[wave] = ws;
  __syncthreads();
  float tot = (red[0] + red[1]) + (red[2] + red[3]);
  float inv = 1.0f / tot;
  #pragma unroll
  for (int q = 0; q < 8; q++) {
    v[q].x *= inv; v[q].y *= inv; v[q].z *= inv; v[q].w *= inv;
    row[q * 256 + t] = v[q];
  }
}

// ---------------------------------------------------------------------------
extern "C" void kernel_launch(void* const* d_in, const int* in_sizes, int n_in,
                              void* d_out, int out_size, void* d_ws, size_t ws_size,
                              hipStream_t stream) {
  const float* freq    = (const float*)d_in[0];   // 1024*4096
  const float* kparams = (const float*)d_in[1];   // 8192*4*6
  const float* temp    = (const float*)d_in[2];   // 1
  // d_in[3] = kmer_idcs (recomputed analytically in-kernel)

  float* out = (float*)d_out;                     // 1024*8192 f32

  short* freqb = (short*)d_ws;                    // 1024*4096 bf16 = 8 MiB
  float* E1t   = (float*)(freqb + (size_t)1024 * 4096);  // 64*8192 f32 = 2 MiB
  float* E2    = E1t + (size_t)64 * 8192;                // 8192*64 f32 = 2 MiB

  prep_kernel<<<6144, 256, 0, stream>>>(freq, freqb, kparams, temp, E1t, E2);
  gemm_kernel<<<dim3(64, 16), 256, 0, stream>>>(freqb, E1t, E2, out);
  norm_kernel<<<1024, 256, 0, stream>>>(out);
}

// Round 11
// 159.054 us; speedup vs baseline: 1.1350x; 1.0084x over previous
//
#include <hip/hip_runtime.h>

// ---------------------------------------------------------------------------
// ConvFeatureExtractor: profile = rownorm( freq @ softmax(matches/T, axis=1)^T )
//   matches[f,i] = Thi[f, i>>6] + Tlo[f, i&63]  (separable!), F=8192, M=4096,
//   B=1024, K=6.  =>  probs[f,i] = e1[f,i>>6] * e2[f,i&63],  Z = (sum e1)(sum e2).
// R17: occupancy identity fix. Per SIMD the MFMA pipe needs 79.5K cyc; a wave
//   is MFMA-busy ~310 of its ~2700-cyc kt period (11.5%), so util is capped at
//   waves/SIMD x 11.5%. R6-R16 all ran 4 waves/SIMD -> the universal 40%
//   plateau was arithmetic, not stalls. New: TM=32 x TN=128 -> grid 2048 =
//   8 blocks/CU (32 waves/CU, 8/SIMD), LDS 12KB/block, acc 16 VGPR
//   (launch_bounds(256,8) pins VGPR<=64). Predicted util 8x11.5 ~ 69%.
//   All else = proven R10 machinery: 3-deep A buffers, 1 barrier/kt, counted
//   vmcnt(3) (1-GLD16 stage + 2 e1 dwords/kt), XOR swizzle, re-associated
//   e1 fold (MFMA on constant e2 frags), XCD remap (rows [128k,128k+128)
//   L2-pinned per XCD; A L2 traffic ~512MB ~ 10 TB/s << 34.5 ceiling).
//   Ledger: R7/8 ports, R14 k-rot, R16 locality = null; R11 no-LDS, R12
//   barrier, R13 cp-norm, R15 1-wave = regress.
// ---------------------------------------------------------------------------

typedef __bf16  bf16x8 __attribute__((ext_vector_type(8)));
typedef float   f32x4  __attribute__((ext_vector_type(4)));

#define GLD16(gp, lp)                                                          \
  __builtin_amdgcn_global_load_lds(                                            \
      (const __attribute__((address_space(1))) void*)(gp),                     \
      (__attribute__((address_space(3))) void*)(lp), 16, 0, 0)

__device__ __forceinline__ short f2bf(float x) {
  unsigned u = __float_as_uint(x);
  unsigned r = (u + 0x7fffu + ((u >> 16) & 1u)) >> 16;   // RNE
  return (short)r;
}

__device__ __forceinline__ float wave_max(float v) {
  #pragma unroll
  for (int off = 32; off; off >>= 1) v = fmaxf(v, __shfl_xor(v, off, 64));
  return v;
}
__device__ __forceinline__ float wave_sum(float v) {
  #pragma unroll
  for (int off = 32; off; off >>= 1) v += __shfl_xor(v, off, 64);
  return v;
}

// ---------------- k1: prep = cast (blocks 0..4095) + tables (4096..6143) ----
__global__ __launch_bounds__(256) void prep_kernel(const float* __restrict__ freq,
                                                   short* __restrict__ freqb,
                                                   const float* __restrict__ kp,
                                                   const float* __restrict__ temp,
                                                   float* __restrict__ E1t,
                                                   float* __restrict__ E2) {
  if (blockIdx.x < 4096) {
    int idx = blockIdx.x * 256 + threadIdx.x;
    float4 v = ((const float4*)freq)[idx];
    short4 o;
    o.x = f2bf(v.x); o.y = f2bf(v.y); o.z = f2bf(v.z); o.w = f2bf(v.w);
    ((short4*)freqb)[idx] = o;
  } else {
    const int t = threadIdx.x;
    const int lane = t & 63, wave = t >> 6;
    const int f = (blockIdx.x - 4096) * 4 + wave;
    const float* P = kp + f * 24;
    const int d0 = (lane >> 4) & 3, d1 = (lane >> 2) & 3, d2 = lane & 3;
    const float thi = P[d0 * 6 + 0] + P[d1 * 6 + 1] + P[d2 * 6 + 2];
    const float tlo = P[d0 * 6 + 3] + P[d1 * 6 + 4] + P[d2 * 6 + 5];
    const float mxhi = wave_max(thi), mxlo = wave_max(tlo);
    const float invT = 1.0f / temp[0];
    const float e1 = __expf((thi - mxhi) * invT);
    const float e2 = __expf((tlo - mxlo) * invT);
    const float s1 = wave_sum(e1), s2 = wave_sum(e2);
    const float invZ = 1.0f / (s1 * s2);
    E1t[lane * 8192 + f] = e1 * invZ;
    E2[(size_t)f * 64 + lane] = e2;
  }
}

// ---------------- k2: GEMM pooled = A(1024x4096) * B^T, B[f,i]=e1[f,i>>6]e2[f,i&63]
// TM=32, TN=128, BK=64; grid 2048 blocks (8/CU), 4 waves 1Mx4N (wave 32x32).
// 3-deep 4KB A buffers (1 GLD16/wave/kt), 1 barrier/kt, counted vmcnt(3).
__global__ __launch_bounds__(256, 8) void gemm_kernel(const short* __restrict__ A,
                                                      const float* __restrict__ E1t,
                                                      const float* __restrict__ E2,
                                                      float* __restrict__ C) {
  __shared__ short As[3][32 * 64];               // 3 x 4 KiB rotating buffers

  const int t = threadIdx.x;
  const int lane = t & 63, wave = t >> 6;
  const int quad = lane >> 4, l16 = lane & 15;

  // XCD remap: d -> XCD k = d%8 owns L in [256k,256k+256) = m-strips
  // {4k..4k+3} = rows [128k,128k+128) (1MB A slice, L2-pinned).
  const int d  = blockIdx.y * 64 + blockIdx.x;
  const int L  = (d & 7) * 256 + (d >> 3);
  const int m0 = (L >> 6) * 32;                  // batch tile (32 strips)
  const int n0 = (L & 63) * 128;                 // filter tile (64 strips)
  const int wn = wave * 32;                      // wave's n-offset

  f32x4 acc[2][2];
  #pragma unroll
  for (int i = 0; i < 2; i++)
    #pragma unroll
    for (int j = 0; j < 2; j++) acc[i][j] = (f32x4){0.f, 0.f, 0.f, 0.f};

  // constant bf16 e2 fragments: lane (l16,quad) of frag (ks,j) covers
  // k = (ks*4+quad)*8 + 0..7 for filter row nrow[j]
  int nrow[2];
  #pragma unroll
  for (int j = 0; j < 2; j++) nrow[j] = n0 + wn + j * 16 + l16;
  bf16x8 e2f[2][2];
  #pragma unroll
  for (int j = 0; j < 2; j++)
    #pragma unroll
    for (int ks = 0; ks < 2; ks++) {
      const float* p = E2 + (size_t)nrow[j] * 64 + (ks * 4 + quad) * 8;
      float4 lo = *(const float4*)p, hi = *(const float4*)(p + 4);
      bf16x8 bb;
      bb[0] = (__bf16)lo.x; bb[1] = (__bf16)lo.y;
      bb[2] = (__bf16)lo.z; bb[3] = (__bf16)lo.w;
      bb[4] = (__bf16)hi.x; bb[5] = (__bf16)hi.y;
      bb[6] = (__bf16)hi.z; bb[7] = (__bf16)hi.w;
      e2f[ks][j] = bb;
    }

  // staging: wave w owns chunk w (rows 8w..8w+7): ONE GLD16 per kt.
  // lane -> row = 8w + (lane>>3), global col swizzled ((lane&7)^(lane>>3))*8.
  const int lane_row = lane >> 3;                      // 0..7 within chunk
  const int src_col = ((lane & 7) ^ lane_row) * 8;     // swizzled global col (shorts)
  const int sw = l16 & 7;                              // reader swizzle key (= row&7)
  const short* Abase = A + (size_t)(m0 + wave * 8 + lane_row) * 4096 + src_col;

  #define STG(kt, buf)                                                         \
    GLD16(Abase + (kt) * 64, &As[buf][wave * 512 + lane * 8])

  // prologue: S(0)[1], e1(0)[2], S(1)[1] -> 4 VMEM outstanding
  STG(0, 0);
  float e1n[2], e1c[2];
  #pragma unroll
  for (int j = 0; j < 2; j++) e1n[j] = E1t[nrow[j]];
  STG(1, 1);

  const f32x4 Z4 = (f32x4){0.f, 0.f, 0.f, 0.f};

  #pragma unroll 1
  for (int kt = 0; kt < 64; ++kt) {
    const int cb = kt % 3;
    const int sb = (kt + 2) % 3;
    const int tn = (kt + 1 > 63) ? 63 : kt + 1;        // tail: dummy reload
    const int ts = (kt + 2 > 63) ? 63 : kt + 2;        // tail: dummy restage

    // queue: [S(kt):1, e1(kt):2, S(kt+1):1] -> vmcnt(3) drains S(kt) only;
    // e1(kt) waited by compiler before its use; S(kt+1) stays in flight.
    asm volatile("s_waitcnt vmcnt(3)" ::: "memory");
    __builtin_amdgcn_s_barrier();                      // publish tile kt

    bf16x8 a[2][2];
    #pragma unroll
    for (int i = 0; i < 2; i++)
      #pragma unroll
      for (int ks = 0; ks < 2; ks++)
        a[i][ks] = *(const bf16x8*)&As[cb][(i * 16 + l16) * 64 +
                                          (((ks * 4 + quad) ^ sw) * 8)];

    #pragma unroll
    for (int j = 0; j < 2; j++) e1c[j] = e1n[j];
    #pragma unroll
    for (int j = 0; j < 2; j++) e1n[j] = E1t[tn * 8192 + nrow[j]];  // +2 VMEM
    STG(ts, sb);                                                    // +1 VMEM

    __builtin_amdgcn_s_setprio(1);
    #pragma unroll
    for (int j = 0; j < 2; j++) {
      const f32x4 s4 = (f32x4){e1c[j], e1c[j], e1c[j], e1c[j]};
      #pragma unroll
      for (int i = 0; i < 2; i++) {
        f32x4 P = __builtin_amdgcn_mfma_f32_16x16x32_bf16(a[i][0], e2f[0][j], Z4, 0, 0, 0);
        P = __builtin_amdgcn_mfma_f32_16x16x32_bf16(a[i][1], e2f[1][j], P, 0, 0, 0);
        acc[i][j] += s4 * P;                           // f32 fold of e1
      }
    }
    __builtin_amdgcn_s_setprio(0);
    // no bottom barrier: restage target (kt+2)%3 last read at kt-1, ordered
    // by this kt's top barrier.
  }

  asm volatile("s_waitcnt vmcnt(0)" ::: "memory");     // drain tail dummies

  // epilogue: C/D layout col=lane&15, row=quad*4+reg
  #pragma unroll
  for (int i = 0; i < 2; i++) {
    #pragma unroll
    for (int r = 0; r < 4; r++) {
      const int brow = m0 + i * 16 + quad * 4 + r;
      float* crow = C + (size_t)brow * 8192 + n0 + wn + l16;
      #pragma unroll
      for (int j = 0; j < 2; j++) crow[j * 16] = acc[i][j][r];
    }
  }
  #undef STG
}

// ---------------- k3: row-normalize d_out (1024 rows of 8192) ----------------
__global__ __launch_bounds__(256) void norm_kernel(float* __restrict__ out) {
  const int b = blockIdx.x;
  const int t = threadIdx.x;
  const int lane = t & 63, wave = t >> 6;
  __shared__ float red[4];

  float4* row = (float4*)(out + (size_t)b * 8192);   // 2048 float4
  float4 v[8];
  float s = 0.0f;
  #pragma unroll
  for (int q = 0; q < 8; q++) {
    v[q] = row[q * 256 + t];
    s += (v[q].x + v[q].y) + (v[q].z + v[q].w);
  }
  float ws = wave_sum(s);
  if (lane == 0) red[wave] = ws;
  __syncthreads();
  float tot = (red[0] + red[1]) + (red[2] + red[3]);
  float inv = 1.0f / tot;
  #pragma unroll
  for (int q = 0; q < 8; q++) {
    v[q].x *= inv; v[q].y *= inv; v[q].z *= inv; v[q].w *= inv;
    row[q * 256 + t] = v[q];
  }
}

// ---------------------------------------------------------------------------
extern "C" void kernel_launch(void* const* d_in, const int* in_sizes, int n_in,
                              void* d_out, int out_size, void* d_ws, size_t ws_size,
                              hipStream_t stream) {
  const float* freq    = (const float*)d_in[0];   // 1024*4096
  const float* kparams = (const float*)d_in[1];   // 8192*4*6
  const float* temp    = (const float*)d_in[2];   // 1
  // d_in[3] = kmer_idcs (recomputed analytically in-kernel)

  float* out = (float*)d_out;                     // 1024*8192 f32

  short* freqb = (short*)d_ws;                    // 1024*4096 bf16 = 8 MiB
  float* E1t   = (float*)(freqb + (size_t)1024 * 4096);  // 64*8192 f32 = 2 MiB
  float* E2    = E1t + (size_t)64 * 8192;                // 8192*64 f32 = 2 MiB

  prep_kernel<<<6144, 256, 0, stream>>>(freq, freqb, kparams, temp, E1t, E2);
  gemm_kernel<<<dim3(64, 32), 256, 0, stream>>>(freqb, E1t, E2, out);
  norm_kernel<<<1024, 256, 0, stream>>>(out);
}